// Round 1
// baseline (133.562 us; speedup 1.0000x reference)
//
#include <hip/hip_runtime.h>

#define EPSF 1e-6f

// ---------------------------------------------------------------------------
// block-wide sum reduction (256 threads = 4 wave64). Valid on thread 0.
// ---------------------------------------------------------------------------
__device__ __forceinline__ float block_reduce_sum(float v) {
#pragma unroll
    for (int off = 32; off > 0; off >>= 1)
        v += __shfl_down(v, off, 64);
    __shared__ float parts[4];
    const int t = threadIdx.x;
    if ((t & 63) == 0) parts[t >> 6] = v;
    __syncthreads();
    float r = 0.f;
    if (t == 0) r = parts[0] + parts[1] + parts[2] + parts[3];
    return r;
}

// ---------------------------------------------------------------------------
// Dense normalizer:  sum_ij exp(gamma_i) * exp(-(||z_i+eps - q_j|| + eps)) * exp(delta_j)
// Each thread owns one i-row; block tiles TILE columns of q in LDS.
// Writes  -partial  (the dense term enters the output negatively).
// ---------------------------------------------------------------------------
template <int TILE>
__global__ __launch_bounds__(256) void dense_kernel(
    const float* __restrict__ z, const float* __restrict__ q,
    const float* __restrict__ gamma, const float* __restrict__ delta,
    float* __restrict__ partial)
{
    __shared__ float4 sq0[TILE];
    __shared__ float4 sq1[TILE];
    __shared__ float  sqn[TILE];
    __shared__ float  sed[TILE];

    const int t   = threadIdx.x;
    const int row = blockIdx.x * 256 + t;
    const int j0  = blockIdx.y * TILE;

    // my z-row, +EPS folded in (matches reference: cdist(z + 1e-6, q))
    const float4 a = *(const float4*)(z + row * 8);
    const float4 b = *(const float4*)(z + row * 8 + 4);
    const float z0 = a.x + EPSF, z1 = a.y + EPSF, z2 = a.z + EPSF, z3 = a.w + EPSF;
    const float z4 = b.x + EPSF, z5 = b.y + EPSF, z6 = b.z + EPSF, z7 = b.w + EPSF;
    const float zn = z0*z0 + z1*z1 + z2*z2 + z3*z3 + z4*z4 + z5*z5 + z6*z6 + z7*z7;
    const float eg = __expf(gamma[row]);

    // stage q tile: rows, squared norms, exp(delta)
    for (int r = t; r < TILE; r += 256) {
        const float4 c = *(const float4*)(q + (size_t)(j0 + r) * 8);
        const float4 d = *(const float4*)(q + (size_t)(j0 + r) * 8 + 4);
        sq0[r] = c;
        sq1[r] = d;
        sqn[r] = c.x*c.x + c.y*c.y + c.z*c.z + c.w*c.w
               + d.x*d.x + d.y*d.y + d.z*d.z + d.w*d.w;
        sed[r] = __expf(delta[j0 + r]);
    }
    __syncthreads();

    float acc = 0.f;
#pragma unroll 4
    for (int r = 0; r < TILE; ++r) {
        const float4 c = sq0[r];
        const float4 d = sq1[r];
        const float dot = z0*c.x + z1*c.y + z2*c.z + z3*c.w
                        + z4*d.x + z5*d.y + z6*d.z + z7*d.w;
        const float d2   = fmaxf(zn + sqn[r] - 2.f * dot, 0.f);
        const float dist = __builtin_amdgcn_sqrtf(d2);      // raw v_sqrt_f32
        acc += sed[r] * __expf(-(dist + EPSF));
    }

    const float v = block_reduce_sum(-eg * acc);
    if (t == 0) partial[blockIdx.y * gridDim.x + blockIdx.x] = v;
}

// ---------------------------------------------------------------------------
// Sparse Poisson term: sum_k w_k * (gamma[i_k] + delta[j_k] - ||z_i - q_j + eps||)
// ---------------------------------------------------------------------------
__global__ __launch_bounds__(256) void sparse_kernel(
    const float* __restrict__ z, const float* __restrict__ q,
    const float* __restrict__ gamma, const float* __restrict__ delta,
    const float* __restrict__ w, const int* __restrict__ si,
    const int* __restrict__ sj, int nnz, float* __restrict__ partial)
{
    const int stride = gridDim.x * blockDim.x;
    float acc = 0.f;
    for (int k = blockIdx.x * blockDim.x + threadIdx.x; k < nnz; k += stride) {
        const int i = si[k];
        const int j = sj[k];
        const float4 a = *(const float4*)(z + (size_t)i * 8);
        const float4 b = *(const float4*)(z + (size_t)i * 8 + 4);
        const float4 c = *(const float4*)(q + (size_t)j * 8);
        const float4 d = *(const float4*)(q + (size_t)j * 8 + 4);
        const float d0 = a.x - c.x + EPSF, d1 = a.y - c.y + EPSF;
        const float d2 = a.z - c.z + EPSF, d3 = a.w - c.w + EPSF;
        const float d4 = b.x - d.x + EPSF, d5 = b.y - d.y + EPSF;
        const float d6 = b.z - d.z + EPSF, d7 = b.w - d.w + EPSF;
        const float s = d0*d0 + d1*d1 + d2*d2 + d3*d3
                      + d4*d4 + d5*d5 + d6*d6 + d7*d7;
        const float dist = __builtin_amdgcn_sqrtf(s);
        acc += w[k] * (gamma[i] + delta[j] - dist);
    }
    const float v = block_reduce_sum(acc);
    if (threadIdx.x == 0) partial[blockIdx.x] = v;
}

// ---------------------------------------------------------------------------
// Final deterministic reduction of all partials -> out[0]
// ---------------------------------------------------------------------------
__global__ __launch_bounds__(256) void reduce_kernel(
    const float* __restrict__ partial, int n, float* __restrict__ out)
{
    float v = 0.f;
    for (int k = threadIdx.x; k < n; k += 256) v += partial[k];
    v = block_reduce_sum(v);
    if (threadIdx.x == 0) out[0] = v;
}

extern "C" void kernel_launch(void* const* d_in, const int* in_sizes, int n_in,
                              void* d_out, int out_size, void* d_ws, size_t ws_size,
                              hipStream_t stream) {
    const float* z     = (const float*)d_in[0];   // [16384, 8]
    const float* q     = (const float*)d_in[1];   // [8192, 8]
    const float* gamma = (const float*)d_in[2];   // [16384]
    const float* delta = (const float*)d_in[3];   // [8192]
    const float* w     = (const float*)d_in[4];   // [nnz]
    const int*   si    = (const int*)d_in[5];     // [nnz]
    const int*   sj    = (const int*)d_in[6];     // [nnz]
    const int    nnz   = in_sizes[4];

    float* out = (float*)d_out;
    float* ws  = (float*)d_ws;

    constexpr int TILE    = 512;
    constexpr int RBLK    = 16384 / 256;          // 64 row blocks
    constexpr int CBLK    = 8192 / TILE;          // 16 col blocks
    constexpr int NDENSE  = RBLK * CBLK;          // 1024 dense partials
    constexpr int NSPARSE = 1024;                 // sparse partials

    dim3 dgrid(RBLK, CBLK);
    dense_kernel<TILE><<<dgrid, 256, 0, stream>>>(z, q, gamma, delta, ws);
    sparse_kernel<<<NSPARSE, 256, 0, stream>>>(z, q, gamma, delta, w, si, sj, nnz,
                                               ws + NDENSE);
    reduce_kernel<<<1, 256, 0, stream>>>(ws, NDENSE + NSPARSE, out);
}

// Round 2
// 64.429 us; speedup vs baseline: 2.0730x; 2.0730x over previous
//
#include <hip/hip_runtime.h>

#define EPSF 1e-6f
#define L2E  1.44269504088896340736f   // log2(e)

constexpr int NT      = 256;
constexpr int TILE    = 128;                 // q columns per tile
constexpr int RPT     = 4;                   // z rows per thread (register tile)
constexpr int ROWS_PB = NT * RPT;            // 1024 rows per block
constexpr int RBLK    = 16384 / ROWS_PB;     // 16
constexpr int CBLK    = 8192 / TILE;         // 64
constexpr int NDENSE  = RBLK * CBLK;         // 1024 dense blocks
constexpr int NSPARSE = 1024;                // sparse blocks

// 48-byte LDS entry: q-row (pre-scaled by log2e), |q'|^2, log2e*(delta-eps)
struct __align__(16) QE { float4 a, b; float qn, sld, p0, p1; };

// ---------------------------------------------------------------------------
__device__ __forceinline__ float block_reduce_sum(float v) {
#pragma unroll
    for (int off = 32; off > 0; off >>= 1) v += __shfl_down(v, off, 64);
    __shared__ float parts[4];
    const int t = threadIdx.x;
    if ((t & 63) == 0) parts[t >> 6] = v;
    __syncthreads();
    float r = 0.f;
    if (t == 0) r = parts[0] + parts[1] + parts[2] + parts[3];
    return r;
}

// ---------------------------------------------------------------------------
// Fused: blocks [0, NDENSE) do the dense normalizer, the rest the sparse term.
// Dense math (log2 domain):
//   term_ij = exp(gamma_i) * 2^( l2e*(delta_j - eps) - sqrt(l2e^2 * d2_ij) )
// with z' = l2e*(z+eps), q' = l2e*q  =>  l2e^2*d2 = |z'|^2 + |q'|^2 - 2 z'.q'
// ---------------------------------------------------------------------------
__global__ __launch_bounds__(NT) void fused_kernel(
    const float* __restrict__ z, const float* __restrict__ q,
    const float* __restrict__ gamma, const float* __restrict__ delta,
    const float* __restrict__ w, const int* __restrict__ si,
    const int* __restrict__ sj, int nnz, float* __restrict__ partial)
{
    __shared__ QE sq[TILE];
    const int t  = threadIdx.x;
    const int id = blockIdx.x;

    if (id < NDENSE) {
        // ---------------- dense path ----------------
        const int bi = id / CBLK;
        const int bj = id % CBLK;
        const int j0 = bj * TILE;

        if (t < TILE) {
            const int j = j0 + t;
            const float4 c  = *(const float4*)(q + (size_t)j * 8);
            const float4 d4 = *(const float4*)(q + (size_t)j * 8 + 4);
            QE e;
            e.a = make_float4(c.x * L2E, c.y * L2E, c.z * L2E, c.w * L2E);
            e.b = make_float4(d4.x * L2E, d4.y * L2E, d4.z * L2E, d4.w * L2E);
            e.qn = e.a.x*e.a.x + e.a.y*e.a.y + e.a.z*e.a.z + e.a.w*e.a.w
                 + e.b.x*e.b.x + e.b.y*e.b.y + e.b.z*e.b.z + e.b.w*e.b.w;
            e.sld = L2E * (delta[j] - EPSF);
            e.p0 = 0.f; e.p1 = 0.f;
            sq[t] = e;
        }
        __syncthreads();

        float zr[RPT][8], zn[RPT], eg[RPT];
#pragma unroll
        for (int k = 0; k < RPT; ++k) {
            const int row = bi * ROWS_PB + k * NT + t;
            const float4 a = *(const float4*)(z + (size_t)row * 8);
            const float4 b = *(const float4*)(z + (size_t)row * 8 + 4);
            zr[k][0] = L2E * (a.x + EPSF); zr[k][1] = L2E * (a.y + EPSF);
            zr[k][2] = L2E * (a.z + EPSF); zr[k][3] = L2E * (a.w + EPSF);
            zr[k][4] = L2E * (b.x + EPSF); zr[k][5] = L2E * (b.y + EPSF);
            zr[k][6] = L2E * (b.z + EPSF); zr[k][7] = L2E * (b.w + EPSF);
            zn[k] = zr[k][0]*zr[k][0] + zr[k][1]*zr[k][1] + zr[k][2]*zr[k][2]
                  + zr[k][3]*zr[k][3] + zr[k][4]*zr[k][4] + zr[k][5]*zr[k][5]
                  + zr[k][6]*zr[k][6] + zr[k][7]*zr[k][7];
            eg[k] = __expf(gamma[row]);
        }

        float acc[RPT] = {0.f, 0.f, 0.f, 0.f};
#pragma unroll 2
        for (int r = 0; r < TILE; ++r) {
            const float4 ea  = sq[r].a;
            const float4 eb  = sq[r].b;
            const float  eqn = sq[r].qn;
            const float  esl = sq[r].sld;
#pragma unroll
            for (int k = 0; k < RPT; ++k) {
                float dot = zr[k][0] * ea.x;
                dot = fmaf(zr[k][1], ea.y, dot);
                dot = fmaf(zr[k][2], ea.z, dot);
                dot = fmaf(zr[k][3], ea.w, dot);
                dot = fmaf(zr[k][4], eb.x, dot);
                dot = fmaf(zr[k][5], eb.y, dot);
                dot = fmaf(zr[k][6], eb.z, dot);
                dot = fmaf(zr[k][7], eb.w, dot);
                float d2 = fmaf(dot, -2.f, zn[k] + eqn);
                d2 = fmaxf(d2, 0.f);
                const float dist = __builtin_amdgcn_sqrtf(d2);
                acc[k] += __builtin_amdgcn_exp2f(esl - dist);
            }
        }

        float s = 0.f;
#pragma unroll
        for (int k = 0; k < RPT; ++k) s = fmaf(eg[k], acc[k], s);
        const float v = block_reduce_sum(-s);
        if (t == 0) partial[id] = v;
    } else {
        // ---------------- sparse path ----------------
        const int sid    = id - NDENSE;
        const int stride = NSPARSE * NT;
        float acc = 0.f;
        for (int k = sid * NT + t; k < nnz; k += stride) {
            const int i = si[k];
            const int j = sj[k];
            const float4 a = *(const float4*)(z + (size_t)i * 8);
            const float4 b = *(const float4*)(z + (size_t)i * 8 + 4);
            const float4 c = *(const float4*)(q + (size_t)j * 8);
            const float4 d = *(const float4*)(q + (size_t)j * 8 + 4);
            const float d0 = a.x - c.x + EPSF, d1 = a.y - c.y + EPSF;
            const float d2 = a.z - c.z + EPSF, d3 = a.w - c.w + EPSF;
            const float d4 = b.x - d.x + EPSF, d5 = b.y - d.y + EPSF;
            const float d6 = b.z - d.z + EPSF, d7 = b.w - d.w + EPSF;
            float s2 = d0 * d0;
            s2 = fmaf(d1, d1, s2); s2 = fmaf(d2, d2, s2); s2 = fmaf(d3, d3, s2);
            s2 = fmaf(d4, d4, s2); s2 = fmaf(d5, d5, s2); s2 = fmaf(d6, d6, s2);
            s2 = fmaf(d7, d7, s2);
            const float dist = __builtin_amdgcn_sqrtf(s2);
            acc += w[k] * (gamma[i] + delta[j] - dist);
        }
        const float v = block_reduce_sum(acc);
        if (t == 0) partial[id] = v;
    }
}

// ---------------------------------------------------------------------------
__global__ __launch_bounds__(256) void reduce_kernel(
    const float* __restrict__ partial, int n, float* __restrict__ out)
{
    float v = 0.f;
    for (int k = threadIdx.x; k < n; k += 256) v += partial[k];
    v = block_reduce_sum(v);
    if (threadIdx.x == 0) out[0] = v;
}

// ---------------------------------------------------------------------------
extern "C" void kernel_launch(void* const* d_in, const int* in_sizes, int n_in,
                              void* d_out, int out_size, void* d_ws, size_t ws_size,
                              hipStream_t stream) {
    const float* z     = (const float*)d_in[0];   // [16384, 8]
    const float* q     = (const float*)d_in[1];   // [8192, 8]
    const float* gamma = (const float*)d_in[2];   // [16384]
    const float* delta = (const float*)d_in[3];   // [8192]
    const float* w     = (const float*)d_in[4];   // [nnz]
    const int*   si    = (const int*)d_in[5];     // [nnz]
    const int*   sj    = (const int*)d_in[6];     // [nnz]
    const int    nnz   = in_sizes[4];

    float* out = (float*)d_out;
    float* ws  = (float*)d_ws;

    fused_kernel<<<NDENSE + NSPARSE, NT, 0, stream>>>(z, q, gamma, delta,
                                                      w, si, sj, nnz, ws);
    reduce_kernel<<<1, 256, 0, stream>>>(ws, NDENSE + NSPARSE, out);
}